// Round 3
// baseline (111.264 us; speedup 1.0000x reference)
//
#include <hip/hip_runtime.h>

#define G 64
#define BLOCK 256
#define NBLOCKS 1280   // 5 blocks/CU * 256 CUs (LDS 32KB -> 5/CU cap), table staged once per block

// Native clang vector types: required by __builtin_nontemporal_load.
typedef float fx4 __attribute__((ext_vector_type(4)));
typedef int   ix4 __attribute__((ext_vector_type(4)));

__device__ __forceinline__ void spline_accum(
    const float2* __restrict__ lds_cp,
    float xin, float yin, int gi, int gj,
    float c1x, float c1y, float& acc)
{
    const float x = xin - floorf(xin);
    const float y = yin - floorf(yin);

    // Catmull-Rom weights: w = [t^3, t^2, t, 1] @ A  (Horner form)
    float wx[4], wy[4];
    wx[0] = ((-0.5f * x + 1.0f) * x - 0.5f) * x;
    wx[1] = (1.5f * x - 2.5f) * x * x + 1.0f;
    wx[2] = ((-1.5f * x + 2.0f) * x + 0.5f) * x;
    wx[3] = (0.5f * x - 0.5f) * x * x;
    wy[0] = ((-0.5f * y + 1.0f) * y - 0.5f) * y;
    wy[1] = (1.5f * y - 2.5f) * y * y + 1.0f;
    wy[2] = ((-1.5f * y + 2.0f) * y + 0.5f) * y;
    wy[3] = (0.5f * y - 0.5f) * y * y;

    const int base = (gi - 1) * G + (gj - 1);
    float s0 = 0.0f, s1 = 0.0f;
    #pragma unroll
    for (int i = 0; i < 4; ++i) {
        float r0 = 0.0f, r1 = 0.0f;
        #pragma unroll
        for (int j = 0; j < 4; ++j) {
            const float2 q = lds_cp[base + i * G + j];
            r0 = fmaf(wy[j], q.x, r0);
            r1 = fmaf(wy[j], q.y, r1);
        }
        s0 = fmaf(wx[i], r0, s0);
        s1 = fmaf(wx[i], r1, s1);
    }

    const float d0 = c1x - s0;
    const float d1 = c1y - s1;
    acc = fmaf(d0, d0, acc);
    acc = fmaf(d1, d1, acc);
}

__global__ __launch_bounds__(BLOCK) void crs_kernel(
    const fx4* __restrict__ ch1,   // 2 points per vec4
    const fx4* __restrict__ ch2,
    const float4* __restrict__ cp, // CP_locs as float4 (G*G/2)
    const ix4* __restrict__ idx,   // 2 points per vec4
    float* __restrict__ out, int npairs)
{
    __shared__ float2 lds_cp[G * G];     // 32 KB
    __shared__ float  wave_sums[BLOCK / 64];

    // Stage CP_locs -> LDS, 16B vectorized: 2048 float4s, 8 per thread.
    {
        float4* lds4 = (float4*)lds_cp;
        #pragma unroll
        for (int i = threadIdx.x; i < (G * G) / 2; i += BLOCK)
            lds4[i] = cp[i];
    }
    __syncthreads();

    float acc0 = 0.0f, acc1 = 0.0f;
    const int stride = NBLOCKS * BLOCK;
    for (int p = blockIdx.x * BLOCK + threadIdx.x; p < npairs; p += stride) {
        // Nontemporal: streaming data shouldn't evict the (cached) table.
        const ix4 ij = __builtin_nontemporal_load(&idx[p]);
        const fx4 c2 = __builtin_nontemporal_load(&ch2[p]);
        const fx4 c1 = __builtin_nontemporal_load(&ch1[p]);

        // Two independent points -> two independent LDS-gather chains (ILP).
        spline_accum(lds_cp, c2.x, c2.y, ij.x, ij.y, c1.x, c1.y, acc0);
        spline_accum(lds_cp, c2.z, c2.w, ij.z, ij.w, c1.z, c1.w, acc1);
    }
    float acc = acc0 + acc1;

    // Wave-64 butterfly reduce, then cross-wave via LDS, one atomic per block.
    #pragma unroll
    for (int off = 32; off > 0; off >>= 1)
        acc += __shfl_down(acc, off, 64);

    const int lane = threadIdx.x & 63;
    const int wave = threadIdx.x >> 6;
    if (lane == 0) wave_sums[wave] = acc;
    __syncthreads();
    if (threadIdx.x == 0) {
        float s = 0.0f;
        #pragma unroll
        for (int w = 0; w < BLOCK / 64; ++w) s += wave_sums[w];
        atomicAdd(out, s);
    }
}

extern "C" void kernel_launch(void* const* d_in, const int* in_sizes, int n_in,
                              void* d_out, int out_size, void* d_ws, size_t ws_size,
                              hipStream_t stream) {
    const fx4*    ch1 = (const fx4*)d_in[0];
    const fx4*    ch2 = (const fx4*)d_in[1];
    const float4* cp  = (const float4*)d_in[2];   // CP_locs (G,G,2) f32
    const ix4*    idx = (const ix4*)d_in[3];
    float* out = (float*)d_out;
    const int npairs = in_sizes[0] / 4;   // N/2 point-pairs (N=2M, even)

    // d_out is poisoned to 0xAA before every timed launch; zero it on-stream.
    (void)hipMemsetAsync(out, 0, sizeof(float), stream);
    crs_kernel<<<NBLOCKS, BLOCK, 0, stream>>>(ch1, ch2, cp, idx, out, npairs);
}